// Round 1
// baseline (240.750 us; speedup 1.0000x reference)
//
#include <hip/hip_runtime.h>

// GAT: B=8, N=1024, D=256, H=8, U=64, HU=512
// out = relu( softmax_k(mask(leaky(as[n,h]+an[k,h]))) @ f  + X@Wr + bias )

#define HU 512
#define NND 1024

// ---------------- Stage 1: fp32 tiled GEMM  C[8192x512] = X[8192x256] @ W[256x512]
// z=0 -> W=kernel      -> feat (workspace)
// z=1 -> W=kernel_res  -> d_out (residual, consumed+overwritten by stage 3)
__global__ __launch_bounds__(256) void proj_gemm(
    const float* __restrict__ X,
    const float* __restrict__ W0,
    const float* __restrict__ W1,
    float* __restrict__ feat,
    float* __restrict__ resid)
{
    const float* __restrict__ W = blockIdx.z ? W1 : W0;
    float* __restrict__ C = blockIdx.z ? resid : feat;
    const int m0 = blockIdx.x * 64;
    const int n0 = blockIdx.y * 64;

    __shared__ __align__(16) float Xs[32][68];  // [k][row], padded
    __shared__ __align__(16) float Ws[32][68];  // [k][col], padded

    const int tid = threadIdx.x;
    const int tx = tid & 15;        // col group
    const int ty = tid >> 4;        // row group
    float acc[4][4] = {};

    for (int k0 = 0; k0 < 256; k0 += 32) {
        // X tile 64x32 -> transposed LDS
        {
            const int r  = tid >> 3;          // 0..31
            const int kc = (tid & 7) * 4;     // 0,4,..28
            float4 v0 = *(const float4*)&X[(m0 + r)      * 256 + k0 + kc];
            float4 v1 = *(const float4*)&X[(m0 + r + 32) * 256 + k0 + kc];
            Xs[kc + 0][r] = v0.x; Xs[kc + 1][r] = v0.y;
            Xs[kc + 2][r] = v0.z; Xs[kc + 3][r] = v0.w;
            Xs[kc + 0][r + 32] = v1.x; Xs[kc + 1][r + 32] = v1.y;
            Xs[kc + 2][r + 32] = v1.z; Xs[kc + 3][r + 32] = v1.w;
        }
        // W tile 32x64 -> natural LDS
        {
            const int kr = tid >> 4;          // 0..15
            const int nc = (tid & 15) * 4;    // 0..60
            float4 w0 = *(const float4*)&W[(k0 + kr)      * 512 + n0 + nc];
            float4 w1 = *(const float4*)&W[(k0 + kr + 16) * 512 + n0 + nc];
            *(float4*)&Ws[kr][nc]      = w0;
            *(float4*)&Ws[kr + 16][nc] = w1;
        }
        __syncthreads();
        #pragma unroll
        for (int kk = 0; kk < 32; kk++) {
            float4 a = *(const float4*)&Xs[kk][ty * 4];
            float4 b = *(const float4*)&Ws[kk][tx * 4];
            const float av[4] = {a.x, a.y, a.z, a.w};
            const float bv[4] = {b.x, b.y, b.z, b.w};
            #pragma unroll
            for (int i = 0; i < 4; i++)
                #pragma unroll
                for (int j = 0; j < 4; j++)
                    acc[i][j] = fmaf(av[i], bv[j], acc[i][j]);
        }
        __syncthreads();
    }
    #pragma unroll
    for (int i = 0; i < 4; i++) {
        float4 o = {acc[i][0], acc[i][1], acc[i][2], acc[i][3]};
        *(float4*)&C[(size_t)(m0 + ty * 4 + i) * 512 + n0 + tx * 4] = o;
    }
}

// ---------------- Stage 2: per-node attention logits (einsum over U=64 = one wave)
__global__ __launch_bounds__(512) void attn_logits(
    const float* __restrict__ feat,
    const float* __restrict__ aks,   // [H*U] flat
    const float* __restrict__ akn,
    float* __restrict__ as_,         // [8192][8]
    float* __restrict__ an_)
{
    const int row = blockIdx.x;
    const int t = threadIdx.x;
    const float fv = feat[(size_t)row * HU + t];
    float a = fv * aks[t];
    float b = fv * akn[t];
    #pragma unroll
    for (int m = 32; m; m >>= 1) {
        a += __shfl_xor(a, m, 64);
        b += __shfl_xor(b, m, 64);
    }
    const int lane = t & 63, h = t >> 6;
    if (lane == 0) {
        as_[row * 8 + h] = a;
        an_[row * 8 + h] = b;
    }
}

// ---------------- Stage 3: per-row sparse softmax + aggregation + residual + relu
__global__ __launch_bounds__(512) void gat_row(
    const float* __restrict__ A,
    const float* __restrict__ feat,
    const float* __restrict__ as_,
    const float* __restrict__ an_,
    const float* __restrict__ bias,
    float* __restrict__ out)   // holds residual on entry
{
    __shared__ int   nE_s;
    __shared__ int   elist[1024];
    __shared__ float ew[1024 * 8];     // [e][h]
    __shared__ float pred[512];
    __shared__ float as_s[8], mh[8], inv[8];

    const int row = blockIdx.x;            // b*1024 + n
    const int b   = row >> 10;
    const int t   = threadIdx.x;

    if (t == 0) nE_s = 0;
    if (t < 8)  as_s[t] = as_[row * 8 + t];
    __syncthreads();

    // compact edge list from dense 0/1 A row
    const float* __restrict__ Arow = A + (size_t)row * 1024;
    #pragma unroll
    for (int kk = 0; kk < 2; kk++) {
        const int k = t + kk * 512;
        if (Arow[k] > 0.5f) {
            int idx = atomicAdd(&nE_s, 1);
            elist[idx] = k;
        }
    }
    __syncthreads();
    const int nE = nE_s;
    const int P  = nE * 8;

    // logits: ew[e*8+h] = leaky(as[h] + an[k_e,h]); track per-head max
    const float* __restrict__ an_b = an_ + (size_t)b * 1024 * 8;
    const int h = t & 7;
    float pmax = -1e30f;
    for (int p = t; p < P; p += 512) {     // p%8 == t%8 == h (512 % 8 == 0)
        const int e = p >> 3;
        const int k = elist[e];
        float x = as_s[h] + an_b[k * 8 + h];
        x = x > 0.f ? x : 0.2f * x;
        ew[p] = x;
        pmax = fmaxf(pmax, x);
    }
    pred[t] = pmax;
    __syncthreads();
    #pragma unroll
    for (int s = 256; s >= 8; s >>= 1) {
        if (t < s) pred[t] = fmaxf(pred[t], pred[t + s]);
        __syncthreads();
    }
    if (t < 8) mh[t] = pred[t];
    __syncthreads();

    // exp + per-head sum
    const float m = mh[h];
    float psum = 0.f;
    for (int p = t; p < P; p += 512) {
        const float w = __expf(ew[p] - m);
        ew[p] = w;
        psum += w;
    }
    pred[t] = psum;
    __syncthreads();
    #pragma unroll
    for (int s = 256; s >= 8; s >>= 1) {
        if (t < s) pred[t] += pred[t + s];
        __syncthreads();
    }
    if (t < 8) inv[t] = 1.0f / pred[t];
    __syncthreads();

    // aggregation: out[row][t] = relu( sum_e coef * f[k_e][t] + resid + bias )
    const int h2 = t >> 6;
    const float* __restrict__ fb = feat + (size_t)b * 1024 * 512;
    float acc = 0.f;
    for (int e = 0; e < nE; e++) {
        const int k = elist[e];
        acc = fmaf(ew[e * 8 + h2], fb[k * 512 + t], acc);
    }
    const size_t ob = (size_t)row * 512 + t;
    const float val = acc * inv[h2] + out[ob] + bias[t];
    out[ob] = fmaxf(val, 0.f);
}

extern "C" void kernel_launch(void* const* d_in, const int* in_sizes, int n_in,
                              void* d_out, int out_size, void* d_ws, size_t ws_size,
                              hipStream_t stream) {
    const float* X    = (const float*)d_in[0];
    const float* A    = (const float*)d_in[1];
    const float* Wk   = (const float*)d_in[2];
    const float* Wr   = (const float*)d_in[3];
    const float* aks  = (const float*)d_in[4];
    const float* akn  = (const float*)d_in[5];
    const float* bias = (const float*)d_in[6];
    float* out  = (float*)d_out;

    float* feat = (float*)d_ws;                 // 8192*512 f32 = 16.8 MB
    float* as_  = feat + (size_t)8192 * 512;    // 8192*8
    float* an_  = as_  + (size_t)8192 * 8;      // 8192*8

    proj_gemm<<<dim3(128, 8, 2), 256, 0, stream>>>(X, Wk, Wr, feat, out);
    attn_logits<<<8192, 512, 0, stream>>>(feat, aks, akn, as_, an_);
    gat_row<<<8192, 512, 0, stream>>>(A, feat, as_, an_, bias, out);
}

// Round 2
// 213.208 us; speedup vs baseline: 1.1292x; 1.1292x over previous
//
#include <hip/hip_runtime.h>
#include <stdint.h>

// GAT: B=8, N=1024, D=256, H=8, U=64, HU=512
// out = relu( softmax_k(mask(leaky(as[n,h]+an[k,h]))) @ f  + X@Wr + bias )

typedef __attribute__((ext_vector_type(8))) short short8;
typedef __attribute__((ext_vector_type(4))) float f32x4;

__device__ __forceinline__ unsigned short f32_to_bf16(float f) {
    unsigned int u = __float_as_uint(f);
    u = (u + 0x7fffu + ((u >> 16) & 1u)) >> 16;   // RNE
    return (unsigned short)u;
}
__device__ __forceinline__ float bf16_to_f32(unsigned short s) {
    return __uint_as_float(((unsigned int)s) << 16);
}
__device__ __forceinline__ void load_lds16(const unsigned short* g, unsigned short* l) {
    __builtin_amdgcn_global_load_lds(
        (const __attribute__((address_space(1))) unsigned int*)g,
        (__attribute__((address_space(3))) unsigned int*)l, 16, 0, 0);
}

// ---------------- packA: Abig[8192][768] = [bf16hi(X) | bf16hi(X) | bf16lo(X)]
__global__ __launch_bounds__(256) void pack_a(const float* __restrict__ X,
                                              unsigned short* __restrict__ Abig) {
    const int idx = blockIdx.x * 256 + threadIdx.x;   // 524288
    const int m  = idx >> 6;
    const int kg = (idx & 63) << 2;
    float4 x = *(const float4*)&X[m * 256 + kg];
    const float xs[4] = {x.x, x.y, x.z, x.w};
    union { unsigned short u[4]; uint64_t q; } hq, lq;
    #pragma unroll
    for (int i = 0; i < 4; i++) {
        unsigned short h = f32_to_bf16(xs[i]);
        hq.u[i] = h;
        lq.u[i] = f32_to_bf16(xs[i] - bf16_to_f32(h));
    }
    unsigned short* r = Abig + (size_t)m * 768;
    *(uint64_t*)(r + kg)       = hq.q;
    *(uint64_t*)(r + 256 + kg) = hq.q;
    *(uint64_t*)(r + 512 + kg) = lq.q;
}

// ---------------- packB: Bpack[n][k], n in [0,1024) (Wk cols | Wr cols), k in [0,768)
// k<256: hi(W[k][n']); 256..511: lo(W[k-256][n']); 512..767: hi(W[k-512][n'])
__global__ __launch_bounds__(256) void pack_b(const float* __restrict__ Wk,
                                              const float* __restrict__ Wr,
                                              unsigned short* __restrict__ Bpack) {
    const int idx = blockIdx.x * 256 + threadIdx.x;   // 786432
    const int n = idx / 768;
    const int k = idx - n * 768;
    const float* __restrict__ W = (n < 512) ? Wk : Wr;
    const int nc = n & 511;
    const float w = W[(k & 255) * 512 + nc];
    unsigned short h = f32_to_bf16(w);
    unsigned short o = (k >= 256 && k < 512) ? f32_to_bf16(w - bf16_to_f32(h)) : h;
    Bpack[idx] = o;
}

// ---------------- Stage 1: bf16 MFMA GEMM  C[8192x1024] = Abig[8192x768] @ Bpack^T
// cols 0..511 -> feat (ws), cols 512..1023 -> resid (d_out)
#define GK 768
__global__ __launch_bounds__(256) void gemm_bf16(const unsigned short* __restrict__ Ab,
                                                 const unsigned short* __restrict__ Bp,
                                                 float* __restrict__ feat,
                                                 float* __restrict__ outr) {
    __shared__ __align__(16) unsigned short As[128 * 32];  // [m][k]
    __shared__ __align__(16) unsigned short Bs[128 * 32];  // [n][k]
    const int tid = threadIdx.x;
    const int lane = tid & 63, wave = tid >> 6;
    const int wr = wave >> 1, wc = wave & 1;               // 2x2 waves of 64x64
    const int m0 = blockIdx.x * 128, n0 = blockIdx.y * 128;
    const int l15 = lane & 15, lhi = lane >> 4;

    f32x4 acc[4][4] = {};

    for (int k0 = 0; k0 < GK; k0 += 32) {
        #pragma unroll
        for (int i = 0; i < 2; i++) {
            const int s = tid + i * 256;
            const int row = s >> 2, kc = (s & 3) * 8;
            load_lds16(Ab + (size_t)(m0 + row) * GK + k0 + kc, &As[s * 8]);
            load_lds16(Bp + (size_t)(n0 + row) * GK + k0 + kc, &Bs[s * 8]);
        }
        asm volatile("s_waitcnt vmcnt(0)" ::: "memory");
        __syncthreads();
        short8 a[4], b[4];
        #pragma unroll
        for (int mi = 0; mi < 4; mi++)
            a[mi] = *(const short8*)&As[(wr * 64 + mi * 16 + l15) * 32 + lhi * 8];
        #pragma unroll
        for (int ni = 0; ni < 4; ni++)
            b[ni] = *(const short8*)&Bs[(wc * 64 + ni * 16 + l15) * 32 + lhi * 8];
        #pragma unroll
        for (int mi = 0; mi < 4; mi++)
            #pragma unroll
            for (int ni = 0; ni < 4; ni++)
                acc[mi][ni] = __builtin_amdgcn_mfma_f32_16x16x32_bf16(a[mi], b[ni], acc[mi][ni], 0, 0, 0);
        __syncthreads();
    }

    const bool isfeat = (n0 < 512);
    float* __restrict__ C = isfeat ? feat : outr;
    const int nc0 = isfeat ? n0 : (n0 - 512);
    #pragma unroll
    for (int mi = 0; mi < 4; mi++)
        #pragma unroll
        for (int ni = 0; ni < 4; ni++) {
            const int col = nc0 + wc * 64 + ni * 16 + l15;
            const int rbase = m0 + wr * 64 + mi * 16 + lhi * 4;
            #pragma unroll
            for (int r = 0; r < 4; r++)
                C[(size_t)(rbase + r) * 512 + col] = acc[mi][ni][r];
        }
}

// ---------------- fallback fp32 GEMM (if ws too small) -- round-1 kernel
__global__ __launch_bounds__(256) void proj_gemm_f32(
    const float* __restrict__ X, const float* __restrict__ W0,
    const float* __restrict__ W1, float* __restrict__ feat, float* __restrict__ resid) {
    const float* __restrict__ W = blockIdx.z ? W1 : W0;
    float* __restrict__ C = blockIdx.z ? resid : feat;
    const int m0 = blockIdx.x * 64, n0 = blockIdx.y * 64;
    __shared__ __align__(16) float Xs[32][68];
    __shared__ __align__(16) float Ws[32][68];
    const int tid = threadIdx.x, tx = tid & 15, ty = tid >> 4;
    float acc[4][4] = {};
    for (int k0 = 0; k0 < 256; k0 += 32) {
        {
            const int r = tid >> 3, kc = (tid & 7) * 4;
            float4 v0 = *(const float4*)&X[(m0 + r) * 256 + k0 + kc];
            float4 v1 = *(const float4*)&X[(m0 + r + 32) * 256 + k0 + kc];
            Xs[kc + 0][r] = v0.x; Xs[kc + 1][r] = v0.y; Xs[kc + 2][r] = v0.z; Xs[kc + 3][r] = v0.w;
            Xs[kc + 0][r + 32] = v1.x; Xs[kc + 1][r + 32] = v1.y; Xs[kc + 2][r + 32] = v1.z; Xs[kc + 3][r + 32] = v1.w;
        }
        {
            const int kr = tid >> 4, nc = (tid & 15) * 4;
            *(float4*)&Ws[kr][nc]      = *(const float4*)&W[(k0 + kr) * 512 + n0 + nc];
            *(float4*)&Ws[kr + 16][nc] = *(const float4*)&W[(k0 + kr + 16) * 512 + n0 + nc];
        }
        __syncthreads();
        #pragma unroll
        for (int kk = 0; kk < 32; kk++) {
            float4 a = *(const float4*)&Xs[kk][ty * 4];
            float4 b = *(const float4*)&Ws[kk][tx * 4];
            const float av[4] = {a.x, a.y, a.z, a.w};
            const float bv[4] = {b.x, b.y, b.z, b.w};
            #pragma unroll
            for (int i = 0; i < 4; i++)
                #pragma unroll
                for (int j = 0; j < 4; j++) acc[i][j] = fmaf(av[i], bv[j], acc[i][j]);
        }
        __syncthreads();
    }
    #pragma unroll
    for (int i = 0; i < 4; i++) {
        float4 o = {acc[i][0], acc[i][1], acc[i][2], acc[i][3]};
        *(float4*)&C[(size_t)(m0 + ty * 4 + i) * 512 + n0 + tx * 4] = o;
    }
}

// ---------------- Stage 2: per-node attention logits
__global__ __launch_bounds__(512) void attn_logits(
    const float* __restrict__ feat, const float* __restrict__ aks,
    const float* __restrict__ akn, float* __restrict__ as_, float* __restrict__ an_) {
    const int row = blockIdx.x, t = threadIdx.x;
    const float fv = feat[(size_t)row * 512 + t];
    float a = fv * aks[t];
    float b = fv * akn[t];
    #pragma unroll
    for (int m = 32; m; m >>= 1) { a += __shfl_xor(a, m, 64); b += __shfl_xor(b, m, 64); }
    const int lane = t & 63, h = t >> 6;
    if (lane == 0) { as_[row * 8 + h] = a; an_[row * 8 + h] = b; }
}

// ---------------- Stage 3: sparse softmax (no max-shift) + aggregation + residual + relu
__global__ __launch_bounds__(512) void gat_row(
    const float* __restrict__ A, const float* __restrict__ feat,
    const float* __restrict__ as_, const float* __restrict__ an_,
    const float* __restrict__ bias, float* __restrict__ out) {
    __shared__ int   nE_s;
    __shared__ int   elist[1024];
    __shared__ float ew[1024 * 8];      // [e][h]
    __shared__ float wred[8][8];
    __shared__ float as_s[8], inv[8];

    const int row = blockIdx.x, b = row >> 10, t = threadIdx.x;
    if (t == 0) nE_s = 0;
    if (t < 8)  as_s[t] = as_[row * 8 + t];
    __syncthreads();

    const float* __restrict__ Arow = A + (size_t)row * 1024;
    #pragma unroll
    for (int kk = 0; kk < 2; kk++) {
        const int k = t + kk * 512;
        if (Arow[k] > 0.5f) elist[atomicAdd(&nE_s, 1)] = k;
    }
    __syncthreads();
    const int nE = nE_s, P = nE * 8;
    const int h = t & 7, lane = t & 63, wv = t >> 6;

    // exp(leaky(as+an)) directly: |logit| <= ~8 so no max-shift needed in fp32
    const float* __restrict__ an_b = an_ + (size_t)b * 8192;
    float psum = 0.f;
    for (int p = t; p < P; p += 512) {        // p%8 == h (512%8==0)
        const int k = elist[p >> 3];
        float x = as_s[h] + an_b[k * 8 + h];
        x = x > 0.f ? x : 0.2f * x;
        const float w = __expf(x);
        ew[p] = w;
        psum += w;
    }
    psum += __shfl_xor(psum, 8, 64);
    psum += __shfl_xor(psum, 16, 64);
    psum += __shfl_xor(psum, 32, 64);
    if (lane < 8) wred[wv][lane] = psum;
    __syncthreads();
    if (t < 8) {
        float s = 0.f;
        #pragma unroll
        for (int w = 0; w < 8; w++) s += wred[w][t];
        inv[t] = 1.0f / s;
    }
    __syncthreads();

    // aggregation: h2 = wave id -> ew read is wave-uniform broadcast, fb read coalesced
    const int h2 = t >> 6;
    const float* __restrict__ fb = feat + (size_t)b * 524288;
    float a0 = 0.f, a1 = 0.f;
    int e = 0;
    for (; e + 2 <= nE; e += 2) {
        const int k0 = elist[e], k1 = elist[e + 1];
        a0 = fmaf(ew[e * 8 + h2],     fb[(size_t)k0 * 512 + t], a0);
        a1 = fmaf(ew[e * 8 + 8 + h2], fb[(size_t)k1 * 512 + t], a1);
    }
    if (e < nE) a0 = fmaf(ew[e * 8 + h2], fb[(size_t)elist[e] * 512 + t], a0);
    const size_t ob = (size_t)row * 512 + t;
    const float val = (a0 + a1) * inv[h2] + out[ob] + bias[t];
    out[ob] = fmaxf(val, 0.f);
}

extern "C" void kernel_launch(void* const* d_in, const int* in_sizes, int n_in,
                              void* d_out, int out_size, void* d_ws, size_t ws_size,
                              hipStream_t stream) {
    const float* X    = (const float*)d_in[0];
    const float* A    = (const float*)d_in[1];
    const float* Wk   = (const float*)d_in[2];
    const float* Wr   = (const float*)d_in[3];
    const float* aks  = (const float*)d_in[4];
    const float* akn  = (const float*)d_in[5];
    const float* bias = (const float*)d_in[6];
    float* out = (float*)d_out;

    float* feat = (float*)d_ws;                       // 8192*512 f32
    float* as_  = feat + (size_t)8192 * 512;
    float* an_  = as_ + 65536;
    unsigned short* Abig  = (unsigned short*)(an_ + 65536);   // [8192][768] bf16
    unsigned short* Bpack = Abig + (size_t)8192 * 768;        // [1024][768] bf16

    const size_t need = ((size_t)(8192 * 512 + 2 * 65536)) * 4
                      + ((size_t)8192 * 768 + (size_t)1024 * 768) * 2;

    if (ws_size >= need) {
        pack_a<<<2048, 256, 0, stream>>>(X, Abig);
        pack_b<<<3072, 256, 0, stream>>>(Wk, Wr, Bpack);
        gemm_bf16<<<dim3(64, 8), 256, 0, stream>>>(Abig, Bpack, feat, out);
    } else {
        proj_gemm_f32<<<dim3(128, 8, 2), 256, 0, stream>>>(X, Wk, Wr, feat, out);
    }
    attn_logits<<<8192, 512, 0, stream>>>(feat, aks, akn, as_, an_);
    gat_row<<<8192, 512, 0, stream>>>(A, feat, as_, an_, bias, out);
}

// Round 5
// 190.608 us; speedup vs baseline: 1.2631x; 1.1186x over previous
//
#include <hip/hip_runtime.h>
#include <stdint.h>

// GAT: B=8, N=1024, D=256, H=8, U=64, HU=512
// out = relu( softmax_k(mask(leaky(as[n,h]+an[k,h]))) @ f  + X@Wr + bias )

typedef __attribute__((ext_vector_type(8))) short short8;
typedef __attribute__((ext_vector_type(4))) float f32x4;
struct __align__(8) us4 { unsigned short x, y, z, w; };

__device__ __forceinline__ unsigned short f32_to_bf16(float f) {
    unsigned int u = __float_as_uint(f);
    u = (u + 0x7fffu + ((u >> 16) & 1u)) >> 16;   // RNE
    return (unsigned short)u;
}
__device__ __forceinline__ float bf16_to_f32(unsigned short s) {
    return __uint_as_float(((unsigned int)s) << 16);
}
__device__ __forceinline__ void load_lds16(const unsigned short* g, unsigned short* l) {
    __builtin_amdgcn_global_load_lds(
        (const __attribute__((address_space(1))) unsigned int*)g,
        (__attribute__((address_space(3))) unsigned int*)l, 16, 0, 0);
}

// ---------------- packA: Abig[8192][768] = [bf16hi(X) | bf16hi(X) | bf16lo(X)]
__global__ __launch_bounds__(256) void pack_a(const float* __restrict__ X,
                                              unsigned short* __restrict__ Abig) {
    const int idx = blockIdx.x * 256 + threadIdx.x;   // 524288
    const int m  = idx >> 6;
    const int kg = (idx & 63) << 2;
    float4 x = *(const float4*)&X[m * 256 + kg];
    const float xs[4] = {x.x, x.y, x.z, x.w};
    union { unsigned short u[4]; uint64_t q; } hq, lq;
    #pragma unroll
    for (int i = 0; i < 4; i++) {
        unsigned short h = f32_to_bf16(xs[i]);
        hq.u[i] = h;
        lq.u[i] = f32_to_bf16(xs[i] - bf16_to_f32(h));
    }
    unsigned short* r = Abig + (size_t)m * 768;
    *(uint64_t*)(r + kg)       = hq.q;
    *(uint64_t*)(r + 256 + kg) = hq.q;
    *(uint64_t*)(r + 512 + kg) = lq.q;
}

// ---------------- packB: Bpack[n][k], n in [0,1024): (Wk cols | Wr cols), k in [0,768)
__global__ __launch_bounds__(256) void pack_b(const float* __restrict__ Wk,
                                              const float* __restrict__ Wr,
                                              unsigned short* __restrict__ Bpack) {
    const int idx = blockIdx.x * 256 + threadIdx.x;   // 786432
    const int n = idx / 768;
    const int k = idx - n * 768;
    const float* __restrict__ W = (n < 512) ? Wk : Wr;
    const int nc = n & 511;
    const float w = W[(k & 255) * 512 + nc];
    unsigned short h = f32_to_bf16(w);
    unsigned short o = (k >= 256 && k < 512) ? f32_to_bf16(w - bf16_to_f32(h)) : h;
    Bpack[idx] = o;
}

// ---------------- attn_ck: collapse attention kernels: ck[d][o], o<8: kernel.aks, o>=8: kernel.akn
__global__ __launch_bounds__(512) void attn_ck(const float* __restrict__ kernel,
                                               const float* __restrict__ aks,
                                               const float* __restrict__ akn,
                                               float* __restrict__ ck) {
    const int d = blockIdx.x, j = threadIdx.x;
    const float kv = kernel[d * 512 + j];
    float a = kv * aks[j];
    float b = kv * akn[j];
    #pragma unroll
    for (int m = 32; m; m >>= 1) { a += __shfl_xor(a, m, 64); b += __shfl_xor(b, m, 64); }
    const int lane = j & 63, h = j >> 6;
    if (lane == 0) { ck[d * 16 + h] = a; ck[d * 16 + 8 + h] = b; }
}

// ---------------- attn_sa: saan[row][0..7]=as, [8..15]=an  =  X @ ck
// 16 rows/block; tile is 16 rows x 64 float4s per row
__global__ __launch_bounds__(256) void attn_sa(const float* __restrict__ X,
                                               const float* __restrict__ ck,
                                               float* __restrict__ saan) {
    __shared__ __align__(16) float Xs[16][260];
    __shared__ __align__(16) float ckL[4096];
    const int t = threadIdx.x, row0 = blockIdx.x * 16;
    #pragma unroll
    for (int i = 0; i < 4; i++) {
        const int q = t + i * 256;                       // float4 index, 0..1023
        const int r = q >> 6, c4 = (q & 63) * 4;         // 64 float4s per row
        *(float4*)&Xs[r][c4] = *(const float4*)&X[(size_t)(row0 + r) * 256 + c4];
        *(float4*)&ckL[q * 4] = *(const float4*)&ck[q * 4];
    }
    __syncthreads();
    const int r = t >> 4, o = t & 15;
    float acc = 0.f;
    #pragma unroll 4
    for (int d = 0; d < 256; d++) acc = fmaf(Xs[r][d], ckL[d * 16 + o], acc);
    saan[(size_t)(row0 + r) * 16 + o] = acc;
}

// ---------------- Stage 1: bf16 MFMA GEMM  C[8192x1024] = Abig @ Bpack^T
// cols 0..511 -> featb (bf16, ws), cols 512..1023 -> resid (f32, d_out)
#define GK 768
__global__ __launch_bounds__(256) void gemm_bf16(const unsigned short* __restrict__ Ab,
                                                 const unsigned short* __restrict__ Bp,
                                                 unsigned short* __restrict__ featb,
                                                 float* __restrict__ outr) {
    __shared__ __align__(16) unsigned short As[128 * 32];  // [m][k]
    __shared__ __align__(16) unsigned short Bs[128 * 32];  // [n][k]
    const int tid = threadIdx.x;
    const int lane = tid & 63, wave = tid >> 6;
    const int wr = wave >> 1, wc = wave & 1;               // 2x2 waves of 64x64
    const int m0 = blockIdx.x * 128, n0 = blockIdx.y * 128;
    const int l15 = lane & 15, lhi = lane >> 4;

    f32x4 acc[4][4] = {};

    for (int k0 = 0; k0 < GK; k0 += 32) {
        #pragma unroll
        for (int i = 0; i < 2; i++) {
            const int s = tid + i * 256;
            const int row = s >> 2, kc = (s & 3) * 8;
            load_lds16(Ab + (size_t)(m0 + row) * GK + k0 + kc, &As[s * 8]);
            load_lds16(Bp + (size_t)(n0 + row) * GK + k0 + kc, &Bs[s * 8]);
        }
        asm volatile("s_waitcnt vmcnt(0)" ::: "memory");
        __syncthreads();
        short8 a[4], b[4];
        #pragma unroll
        for (int mi = 0; mi < 4; mi++)
            a[mi] = *(const short8*)&As[(wr * 64 + mi * 16 + l15) * 32 + lhi * 8];
        #pragma unroll
        for (int ni = 0; ni < 4; ni++)
            b[ni] = *(const short8*)&Bs[(wc * 64 + ni * 16 + l15) * 32 + lhi * 8];
        #pragma unroll
        for (int mi = 0; mi < 4; mi++)
            #pragma unroll
            for (int ni = 0; ni < 4; ni++)
                acc[mi][ni] = __builtin_amdgcn_mfma_f32_16x16x32_bf16(a[mi], b[ni], acc[mi][ni], 0, 0, 0);
        __syncthreads();
    }

    if (n0 < 512) {
        #pragma unroll
        for (int mi = 0; mi < 4; mi++)
            #pragma unroll
            for (int ni = 0; ni < 4; ni++) {
                const int col = n0 + wc * 64 + ni * 16 + l15;
                const int rbase = m0 + wr * 64 + mi * 16 + lhi * 4;
                #pragma unroll
                for (int r = 0; r < 4; r++)
                    featb[(size_t)(rbase + r) * 512 + col] = f32_to_bf16(acc[mi][ni][r]);
            }
    } else {
        #pragma unroll
        for (int mi = 0; mi < 4; mi++)
            #pragma unroll
            for (int ni = 0; ni < 4; ni++) {
                const int col = (n0 - 512) + wc * 64 + ni * 16 + l15;
                const int rbase = m0 + wr * 64 + mi * 16 + lhi * 4;
                #pragma unroll
                for (int r = 0; r < 4; r++)
                    outr[(size_t)(rbase + r) * 512 + col] = acc[mi][ni][r];
            }
    }
}

// ---------------- Stage 3: 4 rows/block, wave-per-row float4 aggregation, bf16 feat
#define CAP 256
__global__ __launch_bounds__(512) void gat_row4(
    const float* __restrict__ A, const unsigned short* __restrict__ featb,
    const float* __restrict__ saan, const float* __restrict__ bias,
    float* __restrict__ out) {
    __shared__ int   elist[4][CAP];
    __shared__ float ew[4][CAP * 8];
    __shared__ float as_s[4][8], inv_s[4][8], wred[4][2][8];
    __shared__ int   cnt[4];

    const int row0 = blockIdx.x * 4, b = row0 >> 10, t = threadIdx.x;
    const int g = t >> 7, tl = t & 127;      // row-group, thread-in-group

    if (t < 4) cnt[t] = 0;
    if (t < 32) as_s[t >> 3][t & 7] = saan[(size_t)(row0 + (t >> 3)) * 16 + (t & 7)];
    __syncthreads();

    // ---- compaction: 128 threads scan this row's 1024 adjacency entries
    {
        const float* __restrict__ Arow = A + (size_t)(row0 + g) * 1024;
        const int k0 = tl * 8;
        float4 a0 = *(const float4*)&Arow[k0];
        float4 a1 = *(const float4*)&Arow[k0 + 4];
        const float av[8] = {a0.x, a0.y, a0.z, a0.w, a1.x, a1.y, a1.z, a1.w};
        #pragma unroll
        for (int i = 0; i < 8; i++)
            if (av[i] > 0.5f) {
                int idx = atomicAdd(&cnt[g], 1);
                if (idx < CAP) elist[g][idx] = k0 + i;
            }
    }
    __syncthreads();

    // ---- logits + exp + per-head sum (128 threads per row; h fixed per thread)
    {
        const int nE = cnt[g], P = nE * 8, h = tl & 7;
        const float* __restrict__ an_b = saan + (size_t)b * 16384;
        float psum = 0.f;
        for (int p = tl; p < P; p += 128) {
            const int k = elist[g][p >> 3];
            float x = as_s[g][h] + an_b[k * 16 + 8 + h];
            x = x > 0.f ? x : 0.2f * x;
            const float w = __expf(x);
            ew[g][p] = w;
            psum += w;
        }
        psum += __shfl_xor(psum, 8, 64);
        psum += __shfl_xor(psum, 16, 64);
        psum += __shfl_xor(psum, 32, 64);
        const int wv = (t >> 6) & 1;
        if ((t & 63) < 8) wred[g][wv][t & 63] = psum;
    }
    __syncthreads();
    if (t < 32) {
        const int r = t >> 3, h = t & 7;
        inv_s[r][h] = 1.0f / (wred[r][0][h] + wred[r][1][h]);
    }
    __syncthreads();

    // ---- aggregation: wave w -> row (w>>1), half-row (w&1); float4 cols, bf16 feat
    {
        const int w = t >> 6, rg = w >> 1, lane = t & 63;
        const int col = (w & 1) * 256 + lane * 4;
        const int hh = col >> 6;
        const int nE = cnt[rg];
        const unsigned short* __restrict__ fb = featb + (size_t)b * 524288;
        float ax = 0.f, ay = 0.f, az = 0.f, aw = 0.f;
        int e = 0;
        for (; e + 2 <= nE; e += 2) {
            const int k0 = elist[rg][e], k1 = elist[rg][e + 1];
            const float c0 = ew[rg][e * 8 + hh], c1 = ew[rg][e * 8 + 8 + hh];
            us4 v0 = *(const us4*)&fb[(size_t)k0 * 512 + col];
            us4 v1 = *(const us4*)&fb[(size_t)k1 * 512 + col];
            ax = fmaf(c0, bf16_to_f32(v0.x), ax); ay = fmaf(c0, bf16_to_f32(v0.y), ay);
            az = fmaf(c0, bf16_to_f32(v0.z), az); aw = fmaf(c0, bf16_to_f32(v0.w), aw);
            ax = fmaf(c1, bf16_to_f32(v1.x), ax); ay = fmaf(c1, bf16_to_f32(v1.y), ay);
            az = fmaf(c1, bf16_to_f32(v1.z), az); aw = fmaf(c1, bf16_to_f32(v1.w), aw);
        }
        if (e < nE) {
            const int k0 = elist[rg][e];
            const float c0 = ew[rg][e * 8 + hh];
            us4 v0 = *(const us4*)&fb[(size_t)k0 * 512 + col];
            ax = fmaf(c0, bf16_to_f32(v0.x), ax); ay = fmaf(c0, bf16_to_f32(v0.y), ay);
            az = fmaf(c0, bf16_to_f32(v0.z), az); aw = fmaf(c0, bf16_to_f32(v0.w), aw);
        }
        const float iv = inv_s[rg][hh];
        const size_t ob = (size_t)(row0 + rg) * 512 + col;
        float4 res = *(const float4*)&out[ob];
        float4 bs  = *(const float4*)&bias[col];
        float4 o;
        o.x = fmaxf(fmaf(ax, iv, res.x + bs.x), 0.f);
        o.y = fmaxf(fmaf(ay, iv, res.y + bs.y), 0.f);
        o.z = fmaxf(fmaf(az, iv, res.z + bs.z), 0.f);
        o.w = fmaxf(fmaf(aw, iv, res.w + bs.w), 0.f);
        *(float4*)&out[ob] = o;
    }
}

extern "C" void kernel_launch(void* const* d_in, const int* in_sizes, int n_in,
                              void* d_out, int out_size, void* d_ws, size_t ws_size,
                              hipStream_t stream) {
    const float* X    = (const float*)d_in[0];
    const float* A    = (const float*)d_in[1];
    const float* Wk   = (const float*)d_in[2];
    const float* Wr   = (const float*)d_in[3];
    const float* aks  = (const float*)d_in[4];
    const float* akn  = (const float*)d_in[5];
    const float* bias = (const float*)d_in[6];
    float* out = (float*)d_out;

    // ws layout (R2 proved ws_size is ample; need ~23.1 MB)
    unsigned short* featb = (unsigned short*)d_ws;            // 8192*512 bf16
    float* saan = (float*)(featb + (size_t)8192 * 512);       // 8192*16 f32
    float* ck   = saan + (size_t)8192 * 16;                   // 256*16 f32
    unsigned short* Abig  = (unsigned short*)(ck + 4096);     // 8192*768 bf16
    unsigned short* Bpack = Abig + (size_t)8192 * 768;        // 1024*768 bf16

    pack_a<<<2048, 256, 0, stream>>>(X, Abig);
    pack_b<<<3072, 256, 0, stream>>>(Wk, Wr, Bpack);
    attn_ck<<<256, 512, 0, stream>>>(Wk, aks, akn, ck);
    attn_sa<<<512, 256, 0, stream>>>(X, ck, saan);
    gemm_bf16<<<dim3(64, 8), 256, 0, stream>>>(Abig, Bpack, featb, out);
    gat_row4<<<2048, 512, 0, stream>>>(A, featb, saan, bias, out);
}

// Round 6
// 183.360 us; speedup vs baseline: 1.3130x; 1.0395x over previous
//
#include <hip/hip_runtime.h>
#include <stdint.h>

// GAT: B=8, N=1024, D=256, H=8, U=64, HU=512
// out = relu( softmax_k(mask(leaky(as[n,h]+an[k,h]))) @ f  + X@Wr + bias )

typedef __attribute__((ext_vector_type(8))) short short8;
typedef __attribute__((ext_vector_type(4))) float f32x4;

__device__ __forceinline__ unsigned short f32_to_bf16(float f) {
    unsigned int u = __float_as_uint(f);
    u = (u + 0x7fffu + ((u >> 16) & 1u)) >> 16;   // RNE
    return (unsigned short)u;
}
__device__ __forceinline__ float bf16_to_f32(unsigned short s) {
    return __uint_as_float(((unsigned int)s) << 16);
}
__device__ __forceinline__ void load_lds16(const unsigned short* g, unsigned short* l) {
    __builtin_amdgcn_global_load_lds(
        (const __attribute__((address_space(1))) unsigned int*)g,
        (__attribute__((address_space(3))) unsigned int*)l, 16, 0, 0);
}

// ---------------- packA: Abig[8192][768] = [bf16hi(X) | bf16hi(X) | bf16lo(X)]
__global__ __launch_bounds__(256) void pack_a(const float* __restrict__ X,
                                              unsigned short* __restrict__ Abig) {
    const int idx = blockIdx.x * 256 + threadIdx.x;   // 524288
    const int m  = idx >> 6;
    const int kg = (idx & 63) << 2;
    float4 x = *(const float4*)&X[m * 256 + kg];
    const float xs[4] = {x.x, x.y, x.z, x.w};
    union { unsigned short u[4]; uint64_t q; } hq, lq;
    #pragma unroll
    for (int i = 0; i < 4; i++) {
        unsigned short h = f32_to_bf16(xs[i]);
        hq.u[i] = h;
        lq.u[i] = f32_to_bf16(xs[i] - bf16_to_f32(h));
    }
    unsigned short* r = Abig + (size_t)m * 768;
    *(uint64_t*)(r + kg)       = hq.q;
    *(uint64_t*)(r + 256 + kg) = hq.q;
    *(uint64_t*)(r + 512 + kg) = lq.q;
}

// ---------------- packB: Bpack[n][k], n in [0,1024): (Wk cols | Wr cols), k in [0,768)
__global__ __launch_bounds__(256) void pack_b(const float* __restrict__ Wk,
                                              const float* __restrict__ Wr,
                                              unsigned short* __restrict__ Bpack) {
    const int idx = blockIdx.x * 256 + threadIdx.x;   // 786432
    const int n = idx / 768;
    const int k = idx - n * 768;
    const float* __restrict__ W = (n < 512) ? Wk : Wr;
    const int nc = n & 511;
    const float w = W[(k & 255) * 512 + nc];
    unsigned short h = f32_to_bf16(w);
    unsigned short o = (k >= 256 && k < 512) ? f32_to_bf16(w - bf16_to_f32(h)) : h;
    Bpack[idx] = o;
}

// ---------------- attn_ck: ck[d][o], o<8: kernel.aks, o>=8: kernel.akn
__global__ __launch_bounds__(512) void attn_ck(const float* __restrict__ kernel,
                                               const float* __restrict__ aks,
                                               const float* __restrict__ akn,
                                               float* __restrict__ ck) {
    const int d = blockIdx.x, j = threadIdx.x;
    const float kv = kernel[d * 512 + j];
    float a = kv * aks[j];
    float b = kv * akn[j];
    #pragma unroll
    for (int m = 32; m; m >>= 1) { a += __shfl_xor(a, m, 64); b += __shfl_xor(b, m, 64); }
    const int lane = j & 63, h = j >> 6;
    if (lane == 0) { ck[d * 16 + h] = a; ck[d * 16 + 8 + h] = b; }
}

// ---------------- attn_sa: saan[row][0..7]=as, [8..15]=an  =  X @ ck
__global__ __launch_bounds__(256) void attn_sa(const float* __restrict__ X,
                                               const float* __restrict__ ck,
                                               float* __restrict__ saan) {
    __shared__ __align__(16) float Xs[16][260];
    __shared__ __align__(16) float ckL[4096];
    const int t = threadIdx.x, row0 = blockIdx.x * 16;
    #pragma unroll
    for (int i = 0; i < 4; i++) {
        const int q = t + i * 256;                       // float4 index, 0..1023
        const int r = q >> 6, c4 = (q & 63) * 4;         // 64 float4s per row
        *(float4*)&Xs[r][c4] = *(const float4*)&X[(size_t)(row0 + r) * 256 + c4];
        *(float4*)&ckL[q * 4] = *(const float4*)&ck[q * 4];
    }
    __syncthreads();
    const int r = t >> 4, o = t & 15;
    float acc = 0.f;
    #pragma unroll 4
    for (int d = 0; d < 256; d++) acc = fmaf(Xs[r][d], ckL[d * 16 + o], acc);
    saan[(size_t)(row0 + r) * 16 + o] = acc;
}

// ---------------- Stage 1: bf16 MFMA GEMM  C[8192x1024] = Abig @ Bpack^T
// cols 0..511 -> featT[b][col][n] (bf16, ws, TRANSPOSED), cols 512..1023 -> resid (f32, d_out)
#define GK 768
__global__ __launch_bounds__(256) void gemm_bf16(const unsigned short* __restrict__ Ab,
                                                 const unsigned short* __restrict__ Bp,
                                                 unsigned short* __restrict__ featT,
                                                 float* __restrict__ outr) {
    __shared__ __align__(16) unsigned short As[128 * 32];  // [m][k]
    __shared__ __align__(16) unsigned short Bs[128 * 32];  // [n][k]
    const int tid = threadIdx.x;
    const int lane = tid & 63, wave = tid >> 6;
    const int wr = wave >> 1, wc = wave & 1;               // 2x2 waves of 64x64
    const int m0 = blockIdx.x * 128, n0 = blockIdx.y * 128;
    const int l15 = lane & 15, lhi = lane >> 4;

    f32x4 acc[4][4] = {};

    for (int k0 = 0; k0 < GK; k0 += 32) {
        #pragma unroll
        for (int i = 0; i < 2; i++) {
            const int s = tid + i * 256;
            const int row = s >> 2, kc = (s & 3) * 8;
            load_lds16(Ab + (size_t)(m0 + row) * GK + k0 + kc, &As[s * 8]);
            load_lds16(Bp + (size_t)(n0 + row) * GK + k0 + kc, &Bs[s * 8]);
        }
        asm volatile("s_waitcnt vmcnt(0)" ::: "memory");
        __syncthreads();
        short8 a[4], b[4];
        #pragma unroll
        for (int mi = 0; mi < 4; mi++)
            a[mi] = *(const short8*)&As[(wr * 64 + mi * 16 + l15) * 32 + lhi * 8];
        #pragma unroll
        for (int ni = 0; ni < 4; ni++)
            b[ni] = *(const short8*)&Bs[(wc * 64 + ni * 16 + l15) * 32 + lhi * 8];
        #pragma unroll
        for (int mi = 0; mi < 4; mi++)
            #pragma unroll
            for (int ni = 0; ni < 4; ni++)
                acc[mi][ni] = __builtin_amdgcn_mfma_f32_16x16x32_bf16(a[mi], b[ni], acc[mi][ni], 0, 0, 0);
        __syncthreads();
    }

    if (n0 < 512) {
        // write transposed: featT[b][col][n_local], 4 consecutive n per lane -> 8B store
        #pragma unroll
        for (int mi = 0; mi < 4; mi++)
            #pragma unroll
            for (int ni = 0; ni < 4; ni++) {
                const int col = n0 + wc * 64 + ni * 16 + l15;
                const int rbase = m0 + wr * 64 + mi * 16 + lhi * 4;
                const int bb = rbase >> 10, nl = rbase & 1023;
                union { unsigned short u[4]; uint64_t q; } pk;
                #pragma unroll
                for (int r = 0; r < 4; r++) pk.u[r] = f32_to_bf16(acc[mi][ni][r]);
                *(uint64_t*)&featT[(size_t)bb * 524288 + (size_t)col * 1024 + nl] = pk.q;
            }
    } else {
        #pragma unroll
        for (int mi = 0; mi < 4; mi++)
            #pragma unroll
            for (int ni = 0; ni < 4; ni++) {
                const int col = (n0 - 512) + wc * 64 + ni * 16 + l15;
                const int rbase = m0 + wr * 64 + mi * 16 + lhi * 4;
                #pragma unroll
                for (int r = 0; r < 4; r++)
                    outr[(size_t)(rbase + r) * 512 + col] = acc[mi][ni][r];
            }
    }
}

// ---------------- Stage 3: fused dense-P MFMA aggregation
// block = (batch = blk%8 [XCD-pinned], 32-row tile), 8 waves = 8 heads, K-loop over 1024
__global__ __launch_bounds__(512) void gat_mfma(
    const float* __restrict__ A, const unsigned short* __restrict__ featT,
    const float* __restrict__ saan, const float* __restrict__ bias,
    float* __restrict__ out) {
    __shared__ float an_s[1024][9];     // padded: conflict-free per-j reads
    __shared__ float A_lds[32][33];     // padded: 2-way max on P-build reads
    __shared__ float inv_lds[8][32];

    const int blk = blockIdx.x;
    const int b  = blk & 7;             // XCD-pinned: batch b -> XCD b (round-robin heuristic)
    const int n0 = (blk >> 3) * 32;
    const int t = threadIdx.x;
    const int w = t >> 6;               // wave = head
    const int lane = t & 63;
    const int l15 = lane & 15, lhi = lane >> 4;

    // stage an[k][h] for whole batch
    #pragma unroll
    for (int i = 0; i < 4; i++) {
        const int idx = i * 512 + t;     // 0..2047
        const int k = idx >> 1, half = (idx & 1) * 4;
        float4 v = *(const float4*)&saan[(size_t)(b * 1024 + k) * 16 + 8 + half];
        an_s[k][half + 0] = v.x; an_s[k][half + 1] = v.y;
        an_s[k][half + 2] = v.z; an_s[k][half + 3] = v.w;
    }
    // as for this lane's A-frag rows (mi*16 + l15), head w
    float as_r[2];
    #pragma unroll
    for (int mi = 0; mi < 2; mi++)
        as_r[mi] = saan[(size_t)(b * 1024 + n0 + mi * 16 + l15) * 16 + w];

    // A-tile prefetch (reg -> LDS, T14 split)
    float4 regA;
    const int sr = t >> 3, sc = (t & 7) * 4;
    if (t < 256)
        regA = *(const float4*)&A[(size_t)(b * 1024 + n0 + sr) * 1024 + sc];

    f32x4 acc[2][4] = {};
    float ps[2] = {0.f, 0.f};
    const unsigned short* __restrict__ fT = featT + (size_t)b * 524288;

    __syncthreads();   // an_s ready

    for (int k0 = 0; k0 < 1024; k0 += 32) {
        if (t < 256) {
            A_lds[sr][sc + 0] = regA.x; A_lds[sr][sc + 1] = regA.y;
            A_lds[sr][sc + 2] = regA.z; A_lds[sr][sc + 3] = regA.w;
            if (k0 + 32 < 1024)
                regA = *(const float4*)&A[(size_t)(b * 1024 + n0 + sr) * 1024 + (k0 + 32) + sc];
        }
        __syncthreads();

        // P-frags in A-operand layout: lane holds rows mi*16+l15, k = lhi*8+j
        union { short8 s8; unsigned int u32[4]; } pa[2];
        #pragma unroll
        for (int mi = 0; mi < 2; mi++) {
            #pragma unroll
            for (int q = 0; q < 4; q++) {
                float pv[2];
                #pragma unroll
                for (int d = 0; d < 2; d++) {
                    const int kk = lhi * 8 + q * 2 + d;
                    float x = as_r[mi] + an_s[k0 + kk][w];
                    x = fmaxf(x, 0.2f * x);                 // leaky
                    const float e = __expf(x);
                    pv[d] = (A_lds[mi * 16 + l15][kk] > 0.5f) ? e : 0.f;
                }
                unsigned int pk;
                asm("v_cvt_pk_bf16_f32 %0, %1, %2" : "=v"(pk) : "v"(pv[0]), "v"(pv[1]));
                pa[mi].u32[q] = pk;
                // rowsum of the ROUNDED coefs -> division normalizes rounding bias
                ps[mi] += __uint_as_float(pk << 16) + __uint_as_float(pk & 0xffff0000u);
            }
        }
        // B-frags straight from featT (16B contiguous, L2-resident per XCD)
        short8 bf[4];
        #pragma unroll
        for (int ni = 0; ni < 4; ni++)
            bf[ni] = *(const short8*)&fT[(size_t)(w * 64 + ni * 16 + l15) * 1024 + k0 + lhi * 8];
        #pragma unroll
        for (int mi = 0; mi < 2; mi++)
            #pragma unroll
            for (int ni = 0; ni < 4; ni++)
                acc[mi][ni] = __builtin_amdgcn_mfma_f32_16x16x32_bf16(pa[mi].s8, bf[ni], acc[mi][ni], 0, 0, 0);
        __syncthreads();
    }

    // rowsum: combine lhi groups (xor 16, 32); publish via LDS (C-layout rows differ)
    #pragma unroll
    for (int mi = 0; mi < 2; mi++) {
        ps[mi] += __shfl_xor(ps[mi], 16, 64);
        ps[mi] += __shfl_xor(ps[mi], 32, 64);
        if (lhi == 0) inv_lds[w][mi * 16 + l15] = 1.0f / ps[mi];
    }
    __syncthreads();

    // epilogue: C-layout row = mi*16 + lhi*4 + r, col = ni*16 + l15
    #pragma unroll
    for (int mi = 0; mi < 2; mi++)
        #pragma unroll
        for (int r = 0; r < 4; r++) {
            const int row_l = mi * 16 + lhi * 4 + r;
            const float iv = inv_lds[w][row_l];
            const size_t rb = (size_t)(b * 1024 + n0 + row_l) * 512 + w * 64;
            #pragma unroll
            for (int ni = 0; ni < 4; ni++) {
                const int col = ni * 16 + l15;
                const float v = fmaf(acc[mi][ni][r], iv, out[rb + col] + bias[w * 64 + col]);
                out[rb + col] = fmaxf(v, 0.f);
            }
        }
}

extern "C" void kernel_launch(void* const* d_in, const int* in_sizes, int n_in,
                              void* d_out, int out_size, void* d_ws, size_t ws_size,
                              hipStream_t stream) {
    const float* X    = (const float*)d_in[0];
    const float* A    = (const float*)d_in[1];
    const float* Wk   = (const float*)d_in[2];
    const float* Wr   = (const float*)d_in[3];
    const float* aks  = (const float*)d_in[4];
    const float* akn  = (const float*)d_in[5];
    const float* bias = (const float*)d_in[6];
    float* out = (float*)d_out;

    // ws: featT 8MB + saan 0.5MB + ck 16KB + Abig 12MB + Bpack 1.5MB ~= 22MB
    unsigned short* featT = (unsigned short*)d_ws;            // [8][512][1024] bf16
    float* saan = (float*)(featT + (size_t)8 * 512 * 1024);   // [8192][16] f32
    float* ck   = saan + (size_t)8192 * 16;                   // [256][16] f32
    unsigned short* Abig  = (unsigned short*)(ck + 4096);     // [8192][768] bf16
    unsigned short* Bpack = Abig + (size_t)8192 * 768;        // [1024][768] bf16

    pack_a<<<2048, 256, 0, stream>>>(X, Abig);
    pack_b<<<3072, 256, 0, stream>>>(Wk, Wr, Bpack);
    attn_ck<<<256, 512, 0, stream>>>(Wk, aks, akn, ck);
    attn_sa<<<512, 256, 0, stream>>>(X, ck, saan);
    gemm_bf16<<<dim3(64, 8), 256, 0, stream>>>(Abig, Bpack, featT, out);
    gat_mfma<<<256, 512, 0, stream>>>(A, featT, saan, bias, out);
}